// Round 21
// baseline (302.615 us; speedup 1.0000x reference)
//
#include <hip/hip_runtime.h>

#define N_NODES 100000
#define E_EDGES 800000
#define IN_F 256
#define D_HEAD 64
#define H_HEADS 4
#define EF_F 64
#define NET_T 8
#define HD 256          // H*D
#define SLOPE 0.2f
#define NTILES ((N_NODES + 63) / 64)
#define NGROUP ((NTILES + 7) / 8)     // groups of 16 blocks (8 tiles x 2 halves)
#define EPT 8                          // edges per thread in hist/scatter
#define HBLOCKS ((E_EDGES + 256 * EPT - 1) / (256 * EPT))   // 391

typedef unsigned short u16;
typedef unsigned long long u64;
typedef __attribute__((ext_vector_type(8))) short bf16x8;
typedef __attribute__((ext_vector_type(4))) float f32x4;

static __device__ __forceinline__ u16 f2bf(float f) {
    unsigned int u = __float_as_uint(f);
    unsigned int r = u + 0x7FFFu + ((u >> 16) & 1u);
    return (u16)(r >> 16);
}
static __device__ __forceinline__ float bf2f(unsigned int u) {
    return __uint_as_float(u << 16);
}

// ---------------- K0: pre-pass: Bfrag build + s_e + 8-wide edge histogram -----------------
// blocks [0,64): Bfrag; block 64: s_e; blocks [65, 65+HBLOCKS): histogram.
// counts is zeroed by a prior hipMemsetAsync (stream-ordered before this kernel).
__global__ void k_pre(const float* __restrict__ W, const float* __restrict__ resW,
                      u16* __restrict__ Bfrag,
                      const float* __restrict__ edge_emb, const float* __restrict__ W_e,
                      const float* __restrict__ a_e, float* __restrict__ s_e,
                      const int* __restrict__ col, int* __restrict__ counts) {
    const int b = blockIdx.x;
    const int tid = threadIdx.x;
    if (b < 64) {
        const int gid = b * 256 + tid;        // 16384 total
        const int lane = gid & 63;
        const int fragid = gid >> 6;          // 0..255 = g*32 + ks*4 + n
        const int n = fragid & 3;
        const int ks = (fragid >> 2) & 7;
        const int g = fragid >> 5;            // 0..7
        const int c = g * 64 + n * 16 + (lane & 15);      // 0..511
        const int k0 = ks * 32 + (lane >> 4) * 8;
        const float* src = (c < HD) ? &W[c] : &resW[c - HD];
        u16 tmp[8];
#pragma unroll
        for (int j = 0; j < 8; ++j)
            tmp[j] = f2bf(src[(size_t)(k0 + j) * HD]);
        *reinterpret_cast<uint4*>(&Bfrag[(size_t)fragid * 512 + lane * 8]) =
            *reinterpret_cast<const uint4*>(tmp);
    } else if (b == 64) {
        const int t  = tid >> 5;              // 0..7
        const int h  = (tid >> 3) & 3;        // 0..3
        const int fc = tid & 7;               // 0..7
        float part = 0.f;
        for (int j = 0; j < 8; ++j) {
            const int f = fc * 8 + j;
            float acc = 0.f;
            for (int k = 0; k < EF_F; ++k)
                acc += edge_emb[t * EF_F + k] * W_e[k * (EF_F * H_HEADS) + h * EF_F + f];
            part += a_e[h * EF_F + f] * acc;
        }
        for (int off = 1; off < 8; off <<= 1)
            part += __shfl_xor(part, off, 64);
        if (fc == 0) s_e[t * H_HEADS + h] = part;
    } else {
        const int base = ((b - 65) * 256 + tid) * EPT;
        if (base + EPT <= E_EDGES) {
            const int4 c0 = *reinterpret_cast<const int4*>(&col[base]);
            const int4 c1 = *reinterpret_cast<const int4*>(&col[base + 4]);
            atomicAdd(&counts[c0.x], 1);
            atomicAdd(&counts[c0.y], 1);
            atomicAdd(&counts[c0.z], 1);
            atomicAdd(&counts[c0.w], 1);
            atomicAdd(&counts[c1.x], 1);
            atomicAdd(&counts[c1.y], 1);
            atomicAdd(&counts[c1.z], 1);
            atomicAdd(&counts[c1.w], 1);
        } else {
            for (int e = base; e < E_EDGES; ++e)
                atomicAdd(&counts[col[e]], 1);
        }
    }
}

// ---------------- K1: fused convert + MFMA GEMM (same-XCD tile pairs, batched staging) ----
__global__ __launch_bounds__(256, 3)
void k_mfma(const float* __restrict__ A, const u16* __restrict__ Bfrag,
            const float* __restrict__ a_l, const float* __restrict__ a_r,
            const float* __restrict__ resb,
            u16* __restrict__ emb_bf, float* __restrict__ s_l, float* __restrict__ s_r,
            u16* __restrict__ res_bf) {
    __shared__ char At[32768];       // 64 rows x 256 bf16, XOR-swizzled
    const int tid = threadIdx.x;
    const int lane = tid & 63;
    const int wv = tid >> 6;         // 0..3
    const int gidx = blockIdx.x >> 4;
    const int x = blockIdx.x & 15;
    const int tile = gidx * 8 + (x & 7);
    if (tile >= NTILES) return;
    const int by = x >> 3;           // 0: emb, 1: residual
    const int wid = (by << 2) | wv;  // global channel-group 0..7
    const int row0 = tile * 64;

    // ---- stage: 2 batches x 8 float4-loads in flight, convert+store after ----
#pragma unroll
    for (int half = 0; half < 2; ++half) {
        float4 v[8];
#pragma unroll
        for (int c = 0; c < 8; ++c) {
            const int lin8 = (half * 8 + c) * 2048 + tid * 8;
            const int r_lin = lin8 >> 9;
            int grow = row0 + r_lin;
            if (grow >= N_NODES) grow = N_NODES - 1;
            const int colb = lin8 & 511;
            v[c] = *reinterpret_cast<const float4*>(&A[(size_t)grow * IN_F + (colb >> 1)]);
        }
#pragma unroll
        for (int c = 0; c < 8; ++c) {
            const int lin8 = (half * 8 + c) * 2048 + tid * 8;
            const int r_lin = lin8 >> 9;
            uint2 o;
            o.x = (unsigned)f2bf(v[c].x) | ((unsigned)f2bf(v[c].y) << 16);
            o.y = (unsigned)f2bf(v[c].z) | ((unsigned)f2bf(v[c].w) << 16);
            *reinterpret_cast<uint2*>(&At[lin8 ^ ((r_lin & 7) << 4)]) = o;
        }
    }
    __syncthreads();

    const int lr = lane & 15;
    const int lg = lane >> 4;
    const int xr = (lr & 7) << 4;                     // swizzle term
    const int klg = lg * 16;                          // byte k-chunk offset in row

    int rowbase[4];
#pragma unroll
    for (int m = 0; m < 4; ++m) rowbase[m] = (m * 16 + lr) * 512;

    const u16* bp = Bfrag + (size_t)wid * 16384 + lane * 8;

    f32x4 acc[4][4] = {};
#pragma unroll
    for (int ks = 0; ks < 8; ++ks) {
        bf16x8 af[4], bfr[4];
        const int kx = ((ks << 6) + klg) ^ xr;        // swizzled intra-row byte
#pragma unroll
        for (int n = 0; n < 4; ++n)
            bfr[n] = *reinterpret_cast<const bf16x8*>(&bp[ks * 2048 + n * 512]);
#pragma unroll
        for (int m = 0; m < 4; ++m)
            af[m] = *reinterpret_cast<const bf16x8*>(&At[rowbase[m] + kx]);
#pragma unroll
        for (int m = 0; m < 4; ++m)
#pragma unroll
            for (int n = 0; n < 4; ++n)
                acc[m][n] = __builtin_amdgcn_mfma_f32_16x16x32_bf16(bfr[n], af[m], acc[m][n], 0, 0, 0);
    }
    // acc[m][n][r]: node=row0+m*16+lr, channel (within group) n*16+lg*4+r

    if (by == 0) {
        const int h = wv;
        float4 alv[4], arv[4];
#pragma unroll
        for (int n = 0; n < 4; ++n) {
            alv[n] = *reinterpret_cast<const float4*>(&a_l[h * D_HEAD + n * 16 + lg * 4]);
            arv[n] = *reinterpret_cast<const float4*>(&a_r[h * D_HEAD + n * 16 + lg * 4]);
        }
#pragma unroll
        for (int m = 0; m < 4; ++m) {
            const int node = row0 + m * 16 + lr;
            float dl = 0.f, dr = 0.f;
            u64 pk[4];
#pragma unroll
            for (int n = 0; n < 4; ++n) {
                float v0 = acc[m][n][0], v1 = acc[m][n][1], v2 = acc[m][n][2], v3 = acc[m][n][3];
                v0 = isnan(v0) ? 0.f : v0;            // nan_to_num
                v1 = isnan(v1) ? 0.f : v1;
                v2 = isnan(v2) ? 0.f : v2;
                v3 = isnan(v3) ? 0.f : v3;
                dl += v0 * alv[n].x + v1 * alv[n].y + v2 * alv[n].z + v3 * alv[n].w;
                dr += v0 * arv[n].x + v1 * arv[n].y + v2 * arv[n].z + v3 * arv[n].w;
                pk[n] = (u64)f2bf(v0) | ((u64)f2bf(v1) << 16) |
                        ((u64)f2bf(v2) << 32) | ((u64)f2bf(v3) << 48);
            }
            if (node < N_NODES) {
                const size_t base = (size_t)node * HD + h * D_HEAD + lg * 4;
#pragma unroll
                for (int n = 0; n < 4; ++n)
                    *reinterpret_cast<u64*>(&emb_bf[base + n * 16]) = pk[n];
            }
            dl += __shfl_xor(dl, 16, 64); dr += __shfl_xor(dr, 16, 64);
            dl += __shfl_xor(dl, 32, 64); dr += __shfl_xor(dr, 32, 64);
            if (lg == 0 && node < N_NODES) {
                s_l[node * H_HEADS + h] = dl;
                s_r[node * H_HEADS + h] = dr;
            }
        }
    } else {
        const int c0 = wv * 64 + lg * 4;
        float4 rb[4];
#pragma unroll
        for (int n = 0; n < 4; ++n)
            rb[n] = *reinterpret_cast<const float4*>(&resb[c0 + n * 16]);
#pragma unroll
        for (int m = 0; m < 4; ++m) {
            const int node = row0 + m * 16 + lr;
            if (node < N_NODES) {
                const size_t base = (size_t)node * HD + c0;
#pragma unroll
                for (int n = 0; n < 4; ++n) {
                    const float v0 = acc[m][n][0] + rb[n].x;
                    const float v1 = acc[m][n][1] + rb[n].y;
                    const float v2 = acc[m][n][2] + rb[n].z;
                    const float v3 = acc[m][n][3] + rb[n].w;
                    const u64 pk = (u64)f2bf(v0) | ((u64)f2bf(v1) << 16) |
                                   ((u64)f2bf(v2) << 32) | ((u64)f2bf(v3) << 48);
                    *reinterpret_cast<u64*>(&res_bf[base + n * 16]) = pk;
                }
            }
        }
    }
}

// ---------------- CSR scan ----------------
__global__ void k_scan1(const int* __restrict__ counts, int* __restrict__ row_ptr,
                        int* __restrict__ partials) {
    __shared__ int sd[256];
    const int t = threadIdx.x, b = blockIdx.x;
    const int base = b * 1024 + t * 4;
    int v[4];
#pragma unroll
    for (int j = 0; j < 4; ++j) v[j] = (base + j < N_NODES) ? counts[base + j] : 0;
    const int s = v[0] + v[1] + v[2] + v[3];
    sd[t] = s;
    __syncthreads();
    for (int off = 1; off < 256; off <<= 1) {
        int y = (t >= off) ? sd[t - off] : 0;
        __syncthreads();
        sd[t] += y;
        __syncthreads();
    }
    int p = sd[t] - s;
#pragma unroll
    for (int j = 0; j < 4; ++j) {
        if (base + j < N_NODES) row_ptr[base + j] = p;
        p += v[j];
    }
    if (t == 255) partials[b] = sd[255];
}

__global__ void k_scan2(int* __restrict__ partials) {
    __shared__ int sd[128];
    const int t = threadIdx.x;
    const int v = (t < 98) ? partials[t] : 0;
    sd[t] = v;
    __syncthreads();
    for (int off = 1; off < 128; off <<= 1) {
        int y = (t >= off) ? sd[t - off] : 0;
        __syncthreads();
        sd[t] += y;
        __syncthreads();
    }
    if (t < 98) partials[t] = sd[t] - v;
}

__global__ void k_scan3(int* __restrict__ row_ptr, int* __restrict__ fill,
                        const int* __restrict__ partials) {
    const int i = blockIdx.x * 256 + threadIdx.x;
    if (i < N_NODES) {
        const int v = row_ptr[i] + partials[i >> 10];
        row_ptr[i] = v;
        fill[i] = v;
    }
    if (i == 0) row_ptr[N_NODES] = E_EDGES;
}

// ---------------- K4: slim scatter, 8 edges/thread (8 atomics in flight) ------------------
__global__ void k_scatter(const int* __restrict__ row, const int* __restrict__ col,
                          const int* __restrict__ tp, int* __restrict__ fill,
                          int* __restrict__ perm_rt) {
    const int base = (blockIdx.x * 256 + threadIdx.x) * EPT;
    if (base + EPT <= E_EDGES) {
        const int4 r0 = *reinterpret_cast<const int4*>(&row[base]);
        const int4 r1 = *reinterpret_cast<const int4*>(&row[base + 4]);
        const int4 c0 = *reinterpret_cast<const int4*>(&col[base]);
        const int4 c1 = *reinterpret_cast<const int4*>(&col[base + 4]);
        const int4 t0 = *reinterpret_cast<const int4*>(&tp[base]);
        const int4 t1 = *reinterpret_cast<const int4*>(&tp[base + 4]);
        int p[8];
        p[0] = atomicAdd(&fill[c0.x], 1);
        p[1] = atomicAdd(&fill[c0.y], 1);
        p[2] = atomicAdd(&fill[c0.z], 1);
        p[3] = atomicAdd(&fill[c0.w], 1);
        p[4] = atomicAdd(&fill[c1.x], 1);
        p[5] = atomicAdd(&fill[c1.y], 1);
        p[6] = atomicAdd(&fill[c1.z], 1);
        p[7] = atomicAdd(&fill[c1.w], 1);
        perm_rt[p[0]] = r0.x | (t0.x << 20);
        perm_rt[p[1]] = r0.y | (t0.y << 20);
        perm_rt[p[2]] = r0.z | (t0.z << 20);
        perm_rt[p[3]] = r0.w | (t0.w << 20);
        perm_rt[p[4]] = r1.x | (t1.x << 20);
        perm_rt[p[5]] = r1.y | (t1.y << 20);
        perm_rt[p[6]] = r1.z | (t1.z << 20);
        perm_rt[p[7]] = r1.w | (t1.w << 20);
    } else {
        for (int e = base; e < E_EDGES; ++e) {
            const int p = atomicAdd(&fill[col[e]], 1);
            perm_rt[p] = row[e] | (tp[e] << 20);
        }
    }
}

// ---------------- K5: aggregation, 2 edges per wave-instruction ---------------------------
// Wave split into two 32-lane slots processing interleaved edges of the same node.
// Each lane reads 16B (8 channels) of emb per edge; 32 lanes cover the 512B row.
// Cross-half shuffle reduction merges slot partial sums before the epilogue.
__global__ __launch_bounds__(256)
void k_aggregate(const int* __restrict__ row_ptr, const int* __restrict__ perm_rt,
                 const float* __restrict__ s_l, const float* __restrict__ s_r,
                 const float* __restrict__ s_e,
                 const u16* __restrict__ emb_bf, const u16* __restrict__ res_bf,
                 float* __restrict__ outp) {
    const int wave = threadIdx.x >> 6;
    const int lane = threadIdx.x & 63;
    const int half = lane >> 5;                    // edge slot 0/1
    const int l5 = lane & 31;
    const int n = blockIdx.x * 4 + wave;           // grid = N/4 exactly
    const int h = l5 >> 3;                         // head of this lane's 8 channels
    const int start = row_ptr[n], end = row_ptr[n + 1];
    const int ch = l5 * 8 + half * 4;              // output float4 base channel
    const size_t o = (size_t)n * HD + ch;
    const u64 rv = *reinterpret_cast<const u64*>(&res_bf[o]);
    const float srh = s_r[n * H_HEADS + h];

    float a[8] = {};
    float den = 0.f;
    for (int i = start; i < end; i += 16) {
        int r[8], t[8]; float sl[8]; uint4 ev[8];
#pragma unroll
        for (int j = 0; j < 8; ++j) {
            int idx = i + 2 * j + half;
            idx = (idx < end) ? idx : (end - 1);
            const int q = perm_rt[idx];
            r[j] = q & 0xFFFFF;
            t[j] = q >> 20;
        }
#pragma unroll
        for (int j = 0; j < 8; ++j)
            sl[j] = s_l[r[j] * H_HEADS + h];
#pragma unroll
        for (int j = 0; j < 8; ++j)
            ev[j] = *reinterpret_cast<const uint4*>(&emb_bf[(size_t)r[j] * HD + l5 * 8]);
#pragma unroll
        for (int j = 0; j < 8; ++j) {
            float lg = sl[j] + srh + s_e[t[j] * H_HEADS + h];
            lg = (lg > 0.f) ? lg : SLOPE * lg;
            float ex = __expf(lg);
            ex = (i + 2 * j + half < end) ? ex : 0.f;
            a[0] += ex * __uint_as_float(ev[j].x << 16);
            a[1] += ex * __uint_as_float(ev[j].x & 0xFFFF0000u);
            a[2] += ex * __uint_as_float(ev[j].y << 16);
            a[3] += ex * __uint_as_float(ev[j].y & 0xFFFF0000u);
            a[4] += ex * __uint_as_float(ev[j].z << 16);
            a[5] += ex * __uint_as_float(ev[j].z & 0xFFFF0000u);
            a[6] += ex * __uint_as_float(ev[j].w << 16);
            a[7] += ex * __uint_as_float(ev[j].w & 0xFFFF0000u);
            den += ex;
        }
    }
    // merge the two slots (they hold partial sums over disjoint edge subsets)
#pragma unroll
    for (int k = 0; k < 8; ++k) a[k] += __shfl_xor(a[k], 32, 64);
    den += __shfl_xor(den, 32, 64);

    const float inv = (den > 0.f) ? 1.f / den : 0.f;
    const int ab = half * 4;
    f32x4 out;
    float x;
    x = a[ab + 0] * inv + bf2f((unsigned)(rv) & 0xFFFFu);       out.x = (x > 0.f) ? x : __expf(x) - 1.f;
    x = a[ab + 1] * inv + bf2f((unsigned)(rv >> 16) & 0xFFFFu); out.y = (x > 0.f) ? x : __expf(x) - 1.f;
    x = a[ab + 2] * inv + bf2f((unsigned)(rv >> 32) & 0xFFFFu); out.z = (x > 0.f) ? x : __expf(x) - 1.f;
    x = a[ab + 3] * inv + bf2f((unsigned)(rv >> 48) & 0xFFFFu); out.w = (x > 0.f) ? x : __expf(x) - 1.f;
    __builtin_nontemporal_store(out, reinterpret_cast<f32x4*>(&outp[o]));
}

extern "C" void kernel_launch(void* const* d_in, const int* in_sizes, int n_in,
                              void* d_out, int out_size, void* d_ws, size_t ws_size,
                              hipStream_t stream) {
    const float* h    = (const float*)d_in[0];
    const float* W    = (const float*)d_in[1];
    const float* W_e  = (const float*)d_in[2];
    const float* eemb = (const float*)d_in[3];
    const float* a_l  = (const float*)d_in[4];
    const float* a_r  = (const float*)d_in[5];
    const float* a_e  = (const float*)d_in[6];
    const float* resW = (const float*)d_in[7];
    const float* resb = (const float*)d_in[8];
    const int* row = (const int*)d_in[9];
    const int* col = (const int*)d_in[10];
    const int* tp  = (const int*)d_in[11];
    float* outp = (float*)d_out;

    char* ws = (char*)d_ws;
    size_t off = 0;
    auto alloc = [&](size_t b) { size_t o = off; off += (b + 255) & ~(size_t)255; return o; };
    u16*  Bfrag   = (u16*)(ws + alloc((size_t)512 * IN_F * 2));
    u16*  emb_bf  = (u16*)(ws + alloc((size_t)N_NODES * HD * 2));
    u16*  res_bf  = (u16*)(ws + alloc((size_t)N_NODES * HD * 2));
    float* s_l    = (float*)(ws + alloc((size_t)N_NODES * H_HEADS * 4));
    float* s_r    = (float*)(ws + alloc((size_t)N_NODES * H_HEADS * 4));
    float* s_e    = (float*)(ws + alloc(NET_T * H_HEADS * 4));
    int*  counts  = (int*)(ws + alloc((size_t)N_NODES * 4));
    int*  row_ptr = (int*)(ws + alloc((size_t)(N_NODES + 1) * 4));
    int*  fill    = (int*)(ws + alloc((size_t)N_NODES * 4));
    int*  perm_rt = (int*)(ws + alloc((size_t)E_EDGES * 4));
    int*  partials= (int*)(ws + alloc(128 * 4));

    (void)hipMemsetAsync(counts, 0, (size_t)N_NODES * 4, stream);
    k_pre<<<65 + HBLOCKS, 256, 0, stream>>>(W, resW, Bfrag, eemb, W_e, a_e, s_e, col, counts);
    k_mfma<<<NGROUP * 16, 256, 0, stream>>>(h, Bfrag, a_l, a_r, resb, emb_bf, s_l, s_r, res_bf);
    k_scan1<<<98, 256, 0, stream>>>(counts, row_ptr, partials);
    k_scan2<<<1, 128, 0, stream>>>(partials);
    k_scan3<<<(N_NODES + 255) / 256, 256, 0, stream>>>(row_ptr, fill, partials);
    k_scatter<<<HBLOCKS, 256, 0, stream>>>(row, col, tp, fill, perm_rt);
    k_aggregate<<<N_NODES / 4, 256, 0, stream>>>(row_ptr, perm_rt, s_l, s_r, s_e,
                                                 emb_bf, res_bf, outp);
}

// Round 22
// 275.623 us; speedup vs baseline: 1.0979x; 1.0979x over previous
//
#include <hip/hip_runtime.h>

#define N_NODES 100000
#define E_EDGES 800000
#define IN_F 256
#define D_HEAD 64
#define H_HEADS 4
#define EF_F 64
#define NET_T 8
#define HD 256          // H*D
#define SLOPE 0.2f
#define NTILES ((N_NODES + 63) / 64)
#define NGROUP ((NTILES + 7) / 8)     // groups of 16 blocks (8 tiles x 2 halves)
#define EPT 8                          // edges per thread in hist/scatter
#define HBLOCKS ((E_EDGES + 256 * EPT - 1) / (256 * EPT))   // 391

typedef unsigned short u16;
typedef unsigned long long u64;
typedef __attribute__((ext_vector_type(8))) short bf16x8;
typedef __attribute__((ext_vector_type(4))) float f32x4;

static __device__ __forceinline__ u16 f2bf(float f) {
    unsigned int u = __float_as_uint(f);
    unsigned int r = u + 0x7FFFu + ((u >> 16) & 1u);
    return (u16)(r >> 16);
}
static __device__ __forceinline__ float bf2f(unsigned int u) {
    return __uint_as_float(u << 16);
}

// ---------------- K0: pre-pass: Bfrag build + s_e + 8-wide edge histogram -----------------
// blocks [0,64): Bfrag; block 64: s_e; blocks [65, 65+HBLOCKS): histogram.
// counts is zeroed by a prior hipMemsetAsync (stream-ordered before this kernel).
__global__ void k_pre(const float* __restrict__ W, const float* __restrict__ resW,
                      u16* __restrict__ Bfrag,
                      const float* __restrict__ edge_emb, const float* __restrict__ W_e,
                      const float* __restrict__ a_e, float* __restrict__ s_e,
                      const int* __restrict__ col, int* __restrict__ counts) {
    const int b = blockIdx.x;
    const int tid = threadIdx.x;
    if (b < 64) {
        const int gid = b * 256 + tid;        // 16384 total
        const int lane = gid & 63;
        const int fragid = gid >> 6;          // 0..255 = g*32 + ks*4 + n
        const int n = fragid & 3;
        const int ks = (fragid >> 2) & 7;
        const int g = fragid >> 5;            // 0..7
        const int c = g * 64 + n * 16 + (lane & 15);      // 0..511
        const int k0 = ks * 32 + (lane >> 4) * 8;
        const float* src = (c < HD) ? &W[c] : &resW[c - HD];
        u16 tmp[8];
#pragma unroll
        for (int j = 0; j < 8; ++j)
            tmp[j] = f2bf(src[(size_t)(k0 + j) * HD]);
        *reinterpret_cast<uint4*>(&Bfrag[(size_t)fragid * 512 + lane * 8]) =
            *reinterpret_cast<const uint4*>(tmp);
    } else if (b == 64) {
        const int t  = tid >> 5;              // 0..7
        const int h  = (tid >> 3) & 3;        // 0..3
        const int fc = tid & 7;               // 0..7
        float part = 0.f;
        for (int j = 0; j < 8; ++j) {
            const int f = fc * 8 + j;
            float acc = 0.f;
            for (int k = 0; k < EF_F; ++k)
                acc += edge_emb[t * EF_F + k] * W_e[k * (EF_F * H_HEADS) + h * EF_F + f];
            part += a_e[h * EF_F + f] * acc;
        }
        for (int off = 1; off < 8; off <<= 1)
            part += __shfl_xor(part, off, 64);
        if (fc == 0) s_e[t * H_HEADS + h] = part;
    } else {
        const int base = ((b - 65) * 256 + tid) * EPT;
        if (base + EPT <= E_EDGES) {
            const int4 c0 = *reinterpret_cast<const int4*>(&col[base]);
            const int4 c1 = *reinterpret_cast<const int4*>(&col[base + 4]);
            atomicAdd(&counts[c0.x], 1);
            atomicAdd(&counts[c0.y], 1);
            atomicAdd(&counts[c0.z], 1);
            atomicAdd(&counts[c0.w], 1);
            atomicAdd(&counts[c1.x], 1);
            atomicAdd(&counts[c1.y], 1);
            atomicAdd(&counts[c1.z], 1);
            atomicAdd(&counts[c1.w], 1);
        } else {
            for (int e = base; e < E_EDGES; ++e)
                atomicAdd(&counts[col[e]], 1);
        }
    }
}

// ---------------- K1: fused convert + MFMA GEMM (same-XCD tile pairs, batched staging) ----
// grid NGROUP*16: g=bid>>4, x=bid&15 -> tile=g*8+(x&7), by=x>>3 (same-XCD pair).
// by=0: emb heads (wave = head); by=1: residual (bf16 store to res_bf).
__global__ __launch_bounds__(256, 3)
void k_mfma(const float* __restrict__ A, const u16* __restrict__ Bfrag,
            const float* __restrict__ a_l, const float* __restrict__ a_r,
            const float* __restrict__ resb,
            u16* __restrict__ emb_bf, float* __restrict__ s_l, float* __restrict__ s_r,
            u16* __restrict__ res_bf) {
    __shared__ char At[32768];       // 64 rows x 256 bf16, XOR-swizzled
    const int tid = threadIdx.x;
    const int lane = tid & 63;
    const int wv = tid >> 6;         // 0..3
    const int gidx = blockIdx.x >> 4;
    const int x = blockIdx.x & 15;
    const int tile = gidx * 8 + (x & 7);
    if (tile >= NTILES) return;
    const int by = x >> 3;           // 0: emb, 1: residual
    const int wid = (by << 2) | wv;  // global channel-group 0..7
    const int row0 = tile * 64;

    // ---- stage: 2 batches x 8 float4-loads in flight, convert+store after ----
#pragma unroll
    for (int half = 0; half < 2; ++half) {
        float4 v[8];
#pragma unroll
        for (int c = 0; c < 8; ++c) {
            const int lin8 = (half * 8 + c) * 2048 + tid * 8;
            const int r_lin = lin8 >> 9;
            int grow = row0 + r_lin;
            if (grow >= N_NODES) grow = N_NODES - 1;
            const int colb = lin8 & 511;
            v[c] = *reinterpret_cast<const float4*>(&A[(size_t)grow * IN_F + (colb >> 1)]);
        }
#pragma unroll
        for (int c = 0; c < 8; ++c) {
            const int lin8 = (half * 8 + c) * 2048 + tid * 8;
            const int r_lin = lin8 >> 9;
            uint2 o;
            o.x = (unsigned)f2bf(v[c].x) | ((unsigned)f2bf(v[c].y) << 16);
            o.y = (unsigned)f2bf(v[c].z) | ((unsigned)f2bf(v[c].w) << 16);
            *reinterpret_cast<uint2*>(&At[lin8 ^ ((r_lin & 7) << 4)]) = o;
        }
    }
    __syncthreads();

    const int lr = lane & 15;
    const int lg = lane >> 4;
    const int xr = (lr & 7) << 4;                     // swizzle term
    const int klg = lg * 16;                          // byte k-chunk offset in row

    int rowbase[4];
#pragma unroll
    for (int m = 0; m < 4; ++m) rowbase[m] = (m * 16 + lr) * 512;

    const u16* bp = Bfrag + (size_t)wid * 16384 + lane * 8;

    f32x4 acc[4][4] = {};
#pragma unroll
    for (int ks = 0; ks < 8; ++ks) {
        bf16x8 af[4], bfr[4];
        const int kx = ((ks << 6) + klg) ^ xr;        // swizzled intra-row byte
#pragma unroll
        for (int n = 0; n < 4; ++n)
            bfr[n] = *reinterpret_cast<const bf16x8*>(&bp[ks * 2048 + n * 512]);
#pragma unroll
        for (int m = 0; m < 4; ++m)
            af[m] = *reinterpret_cast<const bf16x8*>(&At[rowbase[m] + kx]);
#pragma unroll
        for (int m = 0; m < 4; ++m)
#pragma unroll
            for (int n = 0; n < 4; ++n)
                acc[m][n] = __builtin_amdgcn_mfma_f32_16x16x32_bf16(bfr[n], af[m], acc[m][n], 0, 0, 0);
    }
    // acc[m][n][r]: node=row0+m*16+lr, channel (within group) n*16+lg*4+r

    if (by == 0) {
        const int h = wv;
        float4 alv[4], arv[4];
#pragma unroll
        for (int n = 0; n < 4; ++n) {
            alv[n] = *reinterpret_cast<const float4*>(&a_l[h * D_HEAD + n * 16 + lg * 4]);
            arv[n] = *reinterpret_cast<const float4*>(&a_r[h * D_HEAD + n * 16 + lg * 4]);
        }
#pragma unroll
        for (int m = 0; m < 4; ++m) {
            const int node = row0 + m * 16 + lr;
            float dl = 0.f, dr = 0.f;
            u64 pk[4];
#pragma unroll
            for (int n = 0; n < 4; ++n) {
                float v0 = acc[m][n][0], v1 = acc[m][n][1], v2 = acc[m][n][2], v3 = acc[m][n][3];
                v0 = isnan(v0) ? 0.f : v0;            // nan_to_num
                v1 = isnan(v1) ? 0.f : v1;
                v2 = isnan(v2) ? 0.f : v2;
                v3 = isnan(v3) ? 0.f : v3;
                dl += v0 * alv[n].x + v1 * alv[n].y + v2 * alv[n].z + v3 * alv[n].w;
                dr += v0 * arv[n].x + v1 * arv[n].y + v2 * arv[n].z + v3 * arv[n].w;
                pk[n] = (u64)f2bf(v0) | ((u64)f2bf(v1) << 16) |
                        ((u64)f2bf(v2) << 32) | ((u64)f2bf(v3) << 48);
            }
            if (node < N_NODES) {
                const size_t base = (size_t)node * HD + h * D_HEAD + lg * 4;
#pragma unroll
                for (int n = 0; n < 4; ++n)
                    *reinterpret_cast<u64*>(&emb_bf[base + n * 16]) = pk[n];
            }
            dl += __shfl_xor(dl, 16, 64); dr += __shfl_xor(dr, 16, 64);
            dl += __shfl_xor(dl, 32, 64); dr += __shfl_xor(dr, 32, 64);
            if (lg == 0 && node < N_NODES) {
                s_l[node * H_HEADS + h] = dl;
                s_r[node * H_HEADS + h] = dr;
            }
        }
    } else {
        const int c0 = wv * 64 + lg * 4;
        float4 rb[4];
#pragma unroll
        for (int n = 0; n < 4; ++n)
            rb[n] = *reinterpret_cast<const float4*>(&resb[c0 + n * 16]);
#pragma unroll
        for (int m = 0; m < 4; ++m) {
            const int node = row0 + m * 16 + lr;
            if (node < N_NODES) {
                const size_t base = (size_t)node * HD + c0;
#pragma unroll
                for (int n = 0; n < 4; ++n) {
                    const float v0 = acc[m][n][0] + rb[n].x;
                    const float v1 = acc[m][n][1] + rb[n].y;
                    const float v2 = acc[m][n][2] + rb[n].z;
                    const float v3 = acc[m][n][3] + rb[n].w;
                    const u64 pk = (u64)f2bf(v0) | ((u64)f2bf(v1) << 16) |
                                   ((u64)f2bf(v2) << 32) | ((u64)f2bf(v3) << 48);
                    *reinterpret_cast<u64*>(&res_bf[base + n * 16]) = pk;
                }
            }
        }
    }
}

// ---------------- CSR scan ----------------
__global__ void k_scan1(const int* __restrict__ counts, int* __restrict__ row_ptr,
                        int* __restrict__ partials) {
    __shared__ int sd[256];
    const int t = threadIdx.x, b = blockIdx.x;
    const int base = b * 1024 + t * 4;
    int v[4];
#pragma unroll
    for (int j = 0; j < 4; ++j) v[j] = (base + j < N_NODES) ? counts[base + j] : 0;
    const int s = v[0] + v[1] + v[2] + v[3];
    sd[t] = s;
    __syncthreads();
    for (int off = 1; off < 256; off <<= 1) {
        int y = (t >= off) ? sd[t - off] : 0;
        __syncthreads();
        sd[t] += y;
        __syncthreads();
    }
    int p = sd[t] - s;
#pragma unroll
    for (int j = 0; j < 4; ++j) {
        if (base + j < N_NODES) row_ptr[base + j] = p;
        p += v[j];
    }
    if (t == 255) partials[b] = sd[255];
}

__global__ void k_scan2(int* __restrict__ partials) {
    __shared__ int sd[128];
    const int t = threadIdx.x;
    const int v = (t < 98) ? partials[t] : 0;
    sd[t] = v;
    __syncthreads();
    for (int off = 1; off < 128; off <<= 1) {
        int y = (t >= off) ? sd[t - off] : 0;
        __syncthreads();
        sd[t] += y;
        __syncthreads();
    }
    if (t < 98) partials[t] = sd[t] - v;
}

__global__ void k_scan3(int* __restrict__ row_ptr, int* __restrict__ fill,
                        const int* __restrict__ partials) {
    const int i = blockIdx.x * 256 + threadIdx.x;
    if (i < N_NODES) {
        const int v = row_ptr[i] + partials[i >> 10];
        row_ptr[i] = v;
        fill[i] = v;
    }
    if (i == 0) row_ptr[N_NODES] = E_EDGES;
}

// ---------------- K4: slim scatter, 8 edges/thread (8 atomics in flight) ------------------
// perm_rt[p] = row | (tp<<20). Exp/gather work lives in k_aggregate.
__global__ void k_scatter(const int* __restrict__ row, const int* __restrict__ col,
                          const int* __restrict__ tp, int* __restrict__ fill,
                          int* __restrict__ perm_rt) {
    const int base = (blockIdx.x * 256 + threadIdx.x) * EPT;
    if (base + EPT <= E_EDGES) {
        const int4 r0 = *reinterpret_cast<const int4*>(&row[base]);
        const int4 r1 = *reinterpret_cast<const int4*>(&row[base + 4]);
        const int4 c0 = *reinterpret_cast<const int4*>(&col[base]);
        const int4 c1 = *reinterpret_cast<const int4*>(&col[base + 4]);
        const int4 t0 = *reinterpret_cast<const int4*>(&tp[base]);
        const int4 t1 = *reinterpret_cast<const int4*>(&tp[base + 4]);
        int p[8];
        p[0] = atomicAdd(&fill[c0.x], 1);
        p[1] = atomicAdd(&fill[c0.y], 1);
        p[2] = atomicAdd(&fill[c0.z], 1);
        p[3] = atomicAdd(&fill[c0.w], 1);
        p[4] = atomicAdd(&fill[c1.x], 1);
        p[5] = atomicAdd(&fill[c1.y], 1);
        p[6] = atomicAdd(&fill[c1.z], 1);
        p[7] = atomicAdd(&fill[c1.w], 1);
        perm_rt[p[0]] = r0.x | (t0.x << 20);
        perm_rt[p[1]] = r0.y | (t0.y << 20);
        perm_rt[p[2]] = r0.z | (t0.z << 20);
        perm_rt[p[3]] = r0.w | (t0.w << 20);
        perm_rt[p[4]] = r1.x | (t1.x << 20);
        perm_rt[p[5]] = r1.y | (t1.y << 20);
        perm_rt[p[6]] = r1.z | (t1.z << 20);
        perm_rt[p[7]] = r1.w | (t1.w << 20);
    } else {
        for (int e = base; e < E_EDGES; ++e) {
            const int p = atomicAdd(&fill[col[e]], 1);
            perm_rt[p] = row[e] | (tp[e] << 20);
        }
    }
}

// ---------------- K5: per-destination aggregation (masked 8-wide, exp fused) --------------
__global__ __launch_bounds__(256)
void k_aggregate(const int* __restrict__ row_ptr, const int* __restrict__ perm_rt,
                 const float* __restrict__ s_l, const float* __restrict__ s_r,
                 const float* __restrict__ s_e,
                 const u16* __restrict__ emb_bf, const u16* __restrict__ res_bf,
                 float* __restrict__ outp) {
    const int wave = threadIdx.x >> 6;
    const int lane = threadIdx.x & 63;
    const int n = blockIdx.x * 4 + wave;           // grid = N/4 exactly
    const int h = lane >> 4;                       // this lane's head
    const int start = row_ptr[n], end = row_ptr[n + 1];
    const size_t o = (size_t)n * HD + lane * 4;
    const u64 rv = *reinterpret_cast<const u64*>(&res_bf[o]);
    const float srh = s_r[n * H_HEADS + h];

    float a0 = 0.f, a1 = 0.f, a2 = 0.f, a3 = 0.f, den = 0.f;
    for (int i = start; i < end; i += 8) {
        int r[8], t[8]; float sl[8]; u64 ev[8];
#pragma unroll
        for (int j = 0; j < 8; ++j) {
            const int idx = (i + j < end) ? (i + j) : (end - 1);
            const int q = perm_rt[idx];
            r[j] = q & 0xFFFFF;
            t[j] = q >> 20;
        }
#pragma unroll
        for (int j = 0; j < 8; ++j)
            sl[j] = s_l[r[j] * H_HEADS + h];
#pragma unroll
        for (int j = 0; j < 8; ++j)
            ev[j] = *reinterpret_cast<const u64*>(&emb_bf[(size_t)r[j] * HD + lane * 4]);
#pragma unroll
        for (int j = 0; j < 8; ++j) {
            float lg = sl[j] + srh + s_e[t[j] * H_HEADS + h];
            lg = (lg > 0.f) ? lg : SLOPE * lg;
            float ex = __expf(lg);
            ex = (i + j < end) ? ex : 0.f;
            const unsigned lo = (unsigned)ev[j], hi = (unsigned)(ev[j] >> 32);
            a0 += ex * __uint_as_float(lo << 16);
            a1 += ex * __uint_as_float(lo & 0xFFFF0000u);
            a2 += ex * __uint_as_float(hi << 16);
            a3 += ex * __uint_as_float(hi & 0xFFFF0000u);
            den += ex;
        }
    }
    const float inv = (den > 0.f) ? 1.f / den : 0.f;
    f32x4 out;
    float x;
    x = a0 * inv + bf2f((unsigned)(rv) & 0xFFFFu);       out.x = (x > 0.f) ? x : __expf(x) - 1.f;
    x = a1 * inv + bf2f((unsigned)(rv >> 16) & 0xFFFFu); out.y = (x > 0.f) ? x : __expf(x) - 1.f;
    x = a2 * inv + bf2f((unsigned)(rv >> 32) & 0xFFFFu); out.z = (x > 0.f) ? x : __expf(x) - 1.f;
    x = a3 * inv + bf2f((unsigned)(rv >> 48) & 0xFFFFu); out.w = (x > 0.f) ? x : __expf(x) - 1.f;
    __builtin_nontemporal_store(out, reinterpret_cast<f32x4*>(&outp[o]));
}

extern "C" void kernel_launch(void* const* d_in, const int* in_sizes, int n_in,
                              void* d_out, int out_size, void* d_ws, size_t ws_size,
                              hipStream_t stream) {
    const float* h    = (const float*)d_in[0];
    const float* W    = (const float*)d_in[1];
    const float* W_e  = (const float*)d_in[2];
    const float* eemb = (const float*)d_in[3];
    const float* a_l  = (const float*)d_in[4];
    const float* a_r  = (const float*)d_in[5];
    const float* a_e  = (const float*)d_in[6];
    const float* resW = (const float*)d_in[7];
    const float* resb = (const float*)d_in[8];
    const int* row = (const int*)d_in[9];
    const int* col = (const int*)d_in[10];
    const int* tp  = (const int*)d_in[11];
    float* outp = (float*)d_out;

    char* ws = (char*)d_ws;
    size_t off = 0;
    auto alloc = [&](size_t b) { size_t o = off; off += (b + 255) & ~(size_t)255; return o; };
    u16*  Bfrag   = (u16*)(ws + alloc((size_t)512 * IN_F * 2));
    u16*  emb_bf  = (u16*)(ws + alloc((size_t)N_NODES * HD * 2));
    u16*  res_bf  = (u16*)(ws + alloc((size_t)N_NODES * HD * 2));
    float* s_l    = (float*)(ws + alloc((size_t)N_NODES * H_HEADS * 4));
    float* s_r    = (float*)(ws + alloc((size_t)N_NODES * H_HEADS * 4));
    float* s_e    = (float*)(ws + alloc(NET_T * H_HEADS * 4));
    int*  counts  = (int*)(ws + alloc((size_t)N_NODES * 4));
    int*  row_ptr = (int*)(ws + alloc((size_t)(N_NODES + 1) * 4));
    int*  fill    = (int*)(ws + alloc((size_t)N_NODES * 4));
    int*  perm_rt = (int*)(ws + alloc((size_t)E_EDGES * 4));
    int*  partials= (int*)(ws + alloc(128 * 4));

    (void)hipMemsetAsync(counts, 0, (size_t)N_NODES * 4, stream);
    k_pre<<<65 + HBLOCKS, 256, 0, stream>>>(W, resW, Bfrag, eemb, W_e, a_e, s_e, col, counts);
    k_mfma<<<NGROUP * 16, 256, 0, stream>>>(h, Bfrag, a_l, a_r, resb, emb_bf, s_l, s_r, res_bf);
    k_scan1<<<98, 256, 0, stream>>>(counts, row_ptr, partials);
    k_scan2<<<1, 128, 0, stream>>>(partials);
    k_scan3<<<(N_NODES + 255) / 256, 256, 0, stream>>>(row_ptr, fill, partials);
    k_scatter<<<HBLOCKS, 256, 0, stream>>>(row, col, tp, fill, perm_rt);
    k_aggregate<<<N_NODES / 4, 256, 0, stream>>>(row_ptr, perm_rt, s_l, s_r, s_e,
                                                 emb_bf, res_bf, outp);
}